// Round 1
// baseline (238.599 us; speedup 1.0000x reference)
//
#include <hip/hip_runtime.h>

// IF (integrate-and-fire) forward, T=4.
// x: [T*B, C, H, W] f32 viewed as [T][N] with N = total/4.
// Per position: mem = 0.5*thresh; for t: mem += x_t; s = (mem>=thresh)?thresh:0;
// out_t = s; mem -= s.  Memory-bound streaming op (268 MB traffic).

__global__ __launch_bounds__(256) void if_fwd_kernel(
    const float4* __restrict__ x,
    const float* __restrict__ thresh_p,
    float4* __restrict__ out,
    int n4)   // float4 elements per timestep (= N/4)
{
    const float th = thresh_p[0];       // uniform; L2-cached scalar-ish load
    const float m0 = 0.5f * th;

    const int stride = gridDim.x * blockDim.x;
    for (int i = blockIdx.x * blockDim.x + threadIdx.x; i < n4; i += stride) {
        // Issue all 4 timestep loads before the dependent chain (MLP).
        float4 v0 = x[0 * n4 + i];
        float4 v1 = x[1 * n4 + i];
        float4 v2 = x[2 * n4 + i];
        float4 v3 = x[3 * n4 + i];

        float4 m = make_float4(m0, m0, m0, m0);

        float4 s;
        // t = 0
        m.x += v0.x; m.y += v0.y; m.z += v0.z; m.w += v0.w;
        s.x = (m.x >= th) ? th : 0.0f;
        s.y = (m.y >= th) ? th : 0.0f;
        s.z = (m.z >= th) ? th : 0.0f;
        s.w = (m.w >= th) ? th : 0.0f;
        out[0 * n4 + i] = s;
        m.x -= s.x; m.y -= s.y; m.z -= s.z; m.w -= s.w;
        // t = 1
        m.x += v1.x; m.y += v1.y; m.z += v1.z; m.w += v1.w;
        s.x = (m.x >= th) ? th : 0.0f;
        s.y = (m.y >= th) ? th : 0.0f;
        s.z = (m.z >= th) ? th : 0.0f;
        s.w = (m.w >= th) ? th : 0.0f;
        out[1 * n4 + i] = s;
        m.x -= s.x; m.y -= s.y; m.z -= s.z; m.w -= s.w;
        // t = 2
        m.x += v2.x; m.y += v2.y; m.z += v2.z; m.w += v2.w;
        s.x = (m.x >= th) ? th : 0.0f;
        s.y = (m.y >= th) ? th : 0.0f;
        s.z = (m.z >= th) ? th : 0.0f;
        s.w = (m.w >= th) ? th : 0.0f;
        out[2 * n4 + i] = s;
        m.x -= s.x; m.y -= s.y; m.z -= s.z; m.w -= s.w;
        // t = 3
        m.x += v3.x; m.y += v3.y; m.z += v3.z; m.w += v3.w;
        s.x = (m.x >= th) ? th : 0.0f;
        s.y = (m.y >= th) ? th : 0.0f;
        s.z = (m.z >= th) ? th : 0.0f;
        s.w = (m.w >= th) ? th : 0.0f;
        out[3 * n4 + i] = s;
        // (final mem discarded)
    }
}

extern "C" void kernel_launch(void* const* d_in, const int* in_sizes, int n_in,
                              void* d_out, int out_size, void* d_ws, size_t ws_size,
                              hipStream_t stream) {
    const float* x      = (const float*)d_in[0];
    const float* thresh = (const float*)d_in[1];
    float* out          = (float*)d_out;

    const int total   = in_sizes[0];        // 33,554,432 = T*B*C*H*W
    const int n_per_t = total / 4;          // 8,388,608 (T = 4)
    const int n4      = n_per_t / 4;        // 2,097,152 float4 per timestep

    const int block = 256;
    int grid = (n4 + block - 1) / block;
    if (grid > 2048) grid = 2048;           // grid-stride the rest (G11)

    if_fwd_kernel<<<grid, block, 0, stream>>>(
        (const float4*)x, thresh, (float4*)out, n4);
}

// Round 3
// 229.846 us; speedup vs baseline: 1.0381x; 1.0381x over previous
//
#include <hip/hip_runtime.h>

// IF (integrate-and-fire) forward, T=4.
// x: [T*B, C, H, W] f32 viewed as [T][N], N = total/T.
// Per position: mem = 0.5*th; for t: mem += x_t; s = (mem>=th)?th:0; out_t = s; mem -= s.
// Memory-bound streaming (268 MB logical traffic). R3: exact grid, 2 positions/thread
// (8 loads in flight), nontemporal load/store via native clang vector type
// (HIP_vector_type rejected by the builtin).

typedef float f32x4 __attribute__((ext_vector_type(4)));

__device__ __forceinline__ f32x4 if_step(f32x4& m, const f32x4 v, const float th) {
    m += v;
    f32x4 s;
    s.x = (m.x >= th) ? th : 0.0f;
    s.y = (m.y >= th) ? th : 0.0f;
    s.z = (m.z >= th) ? th : 0.0f;
    s.w = (m.w >= th) ? th : 0.0f;
    m -= s;
    return s;
}

__global__ __launch_bounds__(256) void if_fwd_kernel(
    const f32x4* __restrict__ x,
    const float* __restrict__ thresh_p,
    f32x4* __restrict__ out,
    int n4,      // f32x4 elements per timestep
    int half)    // n4/2 — threads cover [0,half), second position at +half
{
    const float th = thresh_p[0];
    const float m0 = 0.5f * th;

    const int i = blockIdx.x * blockDim.x + threadIdx.x;
    if (i >= half) return;
    const int j = i + half;

    // 8 independent loads in flight before any dependent use.
    f32x4 a0 = __builtin_nontemporal_load(x + 0 * n4 + i);
    f32x4 b0 = __builtin_nontemporal_load(x + 0 * n4 + j);
    f32x4 a1 = __builtin_nontemporal_load(x + 1 * n4 + i);
    f32x4 b1 = __builtin_nontemporal_load(x + 1 * n4 + j);
    f32x4 a2 = __builtin_nontemporal_load(x + 2 * n4 + i);
    f32x4 b2 = __builtin_nontemporal_load(x + 2 * n4 + j);
    f32x4 a3 = __builtin_nontemporal_load(x + 3 * n4 + i);
    f32x4 b3 = __builtin_nontemporal_load(x + 3 * n4 + j);

    f32x4 ma = m0, mb = m0;

    // Two independent scan chains, interleaved for ILP.
    f32x4 sa0 = if_step(ma, a0, th);
    f32x4 sb0 = if_step(mb, b0, th);
    __builtin_nontemporal_store(sa0, out + 0 * n4 + i);
    __builtin_nontemporal_store(sb0, out + 0 * n4 + j);

    f32x4 sa1 = if_step(ma, a1, th);
    f32x4 sb1 = if_step(mb, b1, th);
    __builtin_nontemporal_store(sa1, out + 1 * n4 + i);
    __builtin_nontemporal_store(sb1, out + 1 * n4 + j);

    f32x4 sa2 = if_step(ma, a2, th);
    f32x4 sb2 = if_step(mb, b2, th);
    __builtin_nontemporal_store(sa2, out + 2 * n4 + i);
    __builtin_nontemporal_store(sb2, out + 2 * n4 + j);

    f32x4 sa3 = if_step(ma, a3, th);
    f32x4 sb3 = if_step(mb, b3, th);
    __builtin_nontemporal_store(sa3, out + 3 * n4 + i);
    __builtin_nontemporal_store(sb3, out + 3 * n4 + j);
}

extern "C" void kernel_launch(void* const* d_in, const int* in_sizes, int n_in,
                              void* d_out, int out_size, void* d_ws, size_t ws_size,
                              hipStream_t stream) {
    const float* x      = (const float*)d_in[0];
    const float* thresh = (const float*)d_in[1];
    float* out          = (float*)d_out;

    const int total   = in_sizes[0];   // 33,554,432 = T*B*C*H*W (T=4)
    const int n_per_t = total / 4;     // 8,388,608
    const int n4      = n_per_t / 4;   // 2,097,152 f32x4 per timestep
    const int half    = n4 / 2;        // 1,048,576 — 2 positions per thread

    const int block = 256;
    const int grid  = (half + block - 1) / block;   // 4096 blocks

    if_fwd_kernel<<<grid, block, 0, stream>>>(
        (const f32x4*)x, thresh, (f32x4*)out, n4, half);
}